// Round 1
// baseline (304.269 us; speedup 1.0000x reference)
//
#include <hip/hip_runtime.h>

#define NNODES 35
#define NEDGES 1190

// One block per edge, one thread per output channel.
// agg[dst, o] += sum_i h[src, i] * relu(sum_v a[e,v]*W[v,i,o] + b[i,o])
template<int I, int O>
__global__ void edge_kernel(const float* __restrict__ h,      // [N, I]
                            const float* __restrict__ ea,     // [E, 4]
                            const int*   __restrict__ srcs,   // [E]
                            const int*   __restrict__ dsts,   // [E]
                            const float* __restrict__ W,      // [4, I*O]
                            const float* __restrict__ bias,   // [I*O]
                            float*       __restrict__ agg,    // [N, O]
                            float*       __restrict__ cnt)    // [N]
{
    const int e = blockIdx.x;
    const int o = threadIdx.x;
    const int s = srcs[e];
    const int d = dsts[e];

    __shared__ float hs[I];
    __shared__ float as[4];
    if (threadIdx.x < 4) as[threadIdx.x] = ea[e * 4 + threadIdx.x];
    for (int i = threadIdx.x; i < I; i += O) hs[i] = h[s * I + i];
    __syncthreads();

    const float a0 = as[0], a1 = as[1], a2 = as[2], a3 = as[3];
    const float* W0 = W + (size_t)0 * I * O + o;
    const float* W1 = W + (size_t)1 * I * O + o;
    const float* W2 = W + (size_t)2 * I * O + o;
    const float* W3 = W + (size_t)3 * I * O + o;
    const float* bp = bias + o;

    float acc = 0.f;
#pragma unroll 4
    for (int i = 0; i < I; ++i) {
        float w = fmaf(a0, W0[(size_t)i * O],
                  fmaf(a1, W1[(size_t)i * O],
                  fmaf(a2, W2[(size_t)i * O],
                  fmaf(a3, W3[(size_t)i * O], bp[(size_t)i * O]))));
        w = fmaxf(w, 0.f);
        acc = fmaf(hs[i], w, acc);
    }
    atomicAdd(&agg[d * O + o], acc);
    if (o == 0) atomicAdd(&cnt[d], 1.0f);
}

// hout[n,o] = relu(agg[n,o]/max(cnt,1) + sum_i hprev[n,i]*root[i,o] + bias[o])
template<int I, int O>
__global__ void node_kernel(const float* __restrict__ agg,   // [N, O]
                            const float* __restrict__ cnt,   // [N]
                            const float* __restrict__ hprev, // [N, I]
                            const float* __restrict__ root,  // [I, O]
                            const float* __restrict__ bias,  // [O]
                            float*       __restrict__ hout)  // [N, O]
{
    const int n = blockIdx.x;
    const int o = threadIdx.x;
    float r = 0.f;
#pragma unroll 4
    for (int i = 0; i < I; ++i) r = fmaf(hprev[n * I + i], root[i * O + o], r);
    const float c = fmaxf(cnt[n], 1.f);
    hout[n * O + o] = fmaxf(agg[n * O + o] / c + r + bias[o], 0.f);
}

// cbt[a,i] = sum_f |h[i,f] - h[a,f]|   (symmetric)
__global__ void cbt_kernel(const float* __restrict__ h,   // [N, 128]
                           float*       __restrict__ out) // [N, N]
{
    const int idx = blockIdx.x * blockDim.x + threadIdx.x;
    if (idx >= NNODES * NNODES) return;
    const int a = idx / NNODES;
    const int i = idx % NNODES;
    float sum = 0.f;
#pragma unroll 8
    for (int f = 0; f < 128; ++f)
        sum += fabsf(h[i * 128 + f] - h[a * 128 + f]);
    out[idx] = sum;
}

extern "C" void kernel_launch(void* const* d_in, const int* in_sizes, int n_in,
                              void* d_out, int out_size, void* d_ws, size_t ws_size,
                              hipStream_t stream) {
    const float* x       = (const float*)d_in[0];   // [35,1]
    const float* ea      = (const float*)d_in[1];   // [1190,4]
    const int*   eidx    = (const int*)  d_in[2];   // [2,1190]
    const float* mlp1_w  = (const float*)d_in[3];   // [4,512]
    const float* mlp1_b  = (const float*)d_in[4];   // [512]
    const float* root1   = (const float*)d_in[5];   // [1,512]
    const float* bias1   = (const float*)d_in[6];   // [512]
    const float* mlp2_w  = (const float*)d_in[7];   // [4,131072]
    const float* mlp2_b  = (const float*)d_in[8];   // [131072]
    const float* root2   = (const float*)d_in[9];   // [512,256]
    const float* bias2   = (const float*)d_in[10];  // [256]
    const float* mlp3_w  = (const float*)d_in[11];  // [4,32768]
    const float* mlp3_b  = (const float*)d_in[12];  // [32768]
    const float* root3   = (const float*)d_in[13];  // [256,128]
    const float* bias3   = (const float*)d_in[14];  // [128]
    float* out = (float*)d_out;                     // [35,35]

    const int* srcs = eidx;
    const int* dsts = eidx + NEDGES;

    // workspace layout (floats)
    float* ws   = (float*)d_ws;
    float* agg1 = ws;                 // 35*512 = 17920
    float* agg2 = agg1 + 35 * 512;    // 35*256 =  8960
    float* agg3 = agg2 + 35 * 256;    // 35*128 =  4480
    float* cnt1 = agg3 + 35 * 128;    // 35
    float* cnt2 = cnt1 + 35;          // 35
    float* cnt3 = cnt2 + 35;          // 35
    float* h1   = cnt3 + 35;          // 35*512
    float* h2   = h1 + 35 * 512;      // 35*256
    float* h3   = h2 + 35 * 256;      // 35*128

    // zero the accumulator region (agg1..cnt3)
    size_t zero_bytes = (size_t)(35 * 512 + 35 * 256 + 35 * 128 + 3 * 35) * sizeof(float);
    hipMemsetAsync(d_ws, 0, zero_bytes, stream);

    // layer 1: 1 -> 512
    edge_kernel<1, 512><<<NEDGES, 512, 0, stream>>>(x, ea, srcs, dsts, mlp1_w, mlp1_b, agg1, cnt1);
    node_kernel<1, 512><<<NNODES, 512, 0, stream>>>(agg1, cnt1, x, root1, bias1, h1);

    // layer 2: 512 -> 256
    edge_kernel<512, 256><<<NEDGES, 256, 0, stream>>>(h1, ea, srcs, dsts, mlp2_w, mlp2_b, agg2, cnt2);
    node_kernel<512, 256><<<NNODES, 256, 0, stream>>>(agg2, cnt2, h1, root2, bias2, h2);

    // layer 3: 256 -> 128
    edge_kernel<256, 128><<<NEDGES, 128, 0, stream>>>(h2, ea, srcs, dsts, mlp3_w, mlp3_b, agg3, cnt3);
    node_kernel<256, 128><<<NNODES, 128, 0, stream>>>(agg3, cnt3, h2, root3, bias3, h3);

    // pairwise L1 distance
    cbt_kernel<<<(NNODES * NNODES + 255) / 256, 256, 0, stream>>>(h3, out);
}